// Round 2
// baseline (71.617 us; speedup 1.0000x reference)
//
#include <hip/hip_runtime.h>

#define NB   384          // batch
#define ND   256          // embedding dim
#define HB   0x80808080u  // byte-MSB mask
#define KMUL 0x00204081u  // gathers bits {7,15,23,31} -> {28..31}
#define EPSF 1e-6f

// ws layout (floats): [0..16) wlut ; [16 ..) D[384][384] raw distances

// ---------------------------------------------------------------------------
// Kernel B: distance matrix D[i][j] = sqrt(sum((ei-ej+eps)^2)) into ws.
// Block = 4 i-rows x 128 j-cols. Block (0,0) additionally computes the
// ranking histogram -> per-task 1/count weights -> 16-entry wlut in ws[0..16).
// ---------------------------------------------------------------------------
__global__ __launch_bounds__(128) void dist_kernel(
    const float* __restrict__ emb,
    const float* __restrict__ tw,
    const int*   __restrict__ rank,
    float* __restrict__ ws)
{
    __shared__ float    ei[4 * ND];
    __shared__ unsigned hist[20];
    __shared__ double   wp[4];

    const int tid = threadIdx.x;          // 0..127
    const int i0  = blockIdx.x * 4;       // 96 i-tiles
    const int j   = blockIdx.y * 128 + tid; // 3 j-tiles

    // load 4 embedding rows (1024 floats = 256 float4, 2 per thread)
    for (int v = tid; v < ND; v += 128)
        reinterpret_cast<float4*>(ei)[v] =
            reinterpret_cast<const float4*>(emb + (size_t)i0 * ND)[v];
    __syncthreads();

    float acc[4] = {0.f, 0.f, 0.f, 0.f};
    const float4* ej4 = reinterpret_cast<const float4*>(emb + (size_t)j * ND);
    #pragma unroll 4
    for (int d = 0; d < ND / 4; ++d) {
        float4 b = ej4[d];
        #pragma unroll
        for (int ii = 0; ii < 4; ++ii) {
            float4 a = reinterpret_cast<const float4*>(ei + ii * ND)[d];
            float dx = a.x - b.x + EPSF;
            float dy = a.y - b.y + EPSF;
            float dz = a.z - b.z + EPSF;
            float dw = a.w - b.w + EPSF;
            acc[ii] = fmaf(dx, dx, acc[ii]);
            acc[ii] = fmaf(dy, dy, acc[ii]);
            acc[ii] = fmaf(dz, dz, acc[ii]);
            acc[ii] = fmaf(dw, dw, acc[ii]);
        }
    }
    float* D = ws + 16;
    #pragma unroll
    for (int ii = 0; ii < 4; ++ii)
        D[(size_t)(i0 + ii) * NB + j] = sqrtf(acc[ii]);

    // ---- block (0,0): wlut precompute (analytic counts from rank histogram)
    if (blockIdx.x == 0 && blockIdx.y == 0) {
        if (tid < 20) hist[tid] = 0u;
        __syncthreads();
        for (int e = tid; e < NB * 4; e += 128)
            atomicAdd(&hist[(e & 3) * 5 + rank[e]], 1u);
        __syncthreads();
        if (tid < 4) {
            double c = 0.0;
            unsigned below = 0;
            #pragma unroll
            for (int v = 0; v < 5; ++v) {
                unsigned hv = hist[tid * 5 + v];
                unsigned above = (unsigned)NB - below - hv;
                c += (double)hv * (double)below * (double)above;
                below += hv;
            }
            wp[tid] = (c > 0.0) ? (double)tw[tid] / c : 0.0;
        }
        __syncthreads();
        if (tid < 16) {
            double w = 0.0;
            if (tid & 1) w += wp[0];
            if (tid & 2) w += wp[1];
            if (tid & 4) w += wp[2];
            if (tid & 8) w += wp[3];
            ws[tid] = (float)w;            // wlut[0] == 0 absorbs masked triples
        }
    }
}

// ---------------------------------------------------------------------------
// Kernel C: total += relu(D[i][j] - D[i][k] + 1) * wlut[taskbits(i,j,k)]
// Block = (i, 48-wide j-slice); thread owns k = tid and tid+192.
// 3072 blocks x 3 waves = 9216 waves (~8/SIMD) for latency hiding.
// ---------------------------------------------------------------------------
__global__ __launch_bounds__(192, 4) void mtrl_kernel(
    const int*   __restrict__ rank,
    const float* __restrict__ ws,
    float* __restrict__ out)
{
    __shared__ float4 jd[48];   // {D[i][j]+1, HB - rp_j, gt[i,j] bits, 0}
    __shared__ float  wl[16];
    __shared__ float  red[3];

    const int tid = threadIdx.x;
    const int bi  = blockIdx.x >> 3;
    const int j0  = (blockIdx.x & 7) * 48;
    const float* D = ws + 16;

    if (tid < 16) wl[tid] = ws[tid];

    // packed ranks of row i (uniform -> scalar path)
    const int4 ri4 = *reinterpret_cast<const int4*>(rank + bi * 4);
    const unsigned rpi = (unsigned)ri4.x | ((unsigned)ri4.y << 8) |
                         ((unsigned)ri4.z << 16) | ((unsigned)ri4.w << 24);
    const unsigned hmi = HB - rpi;

    if (tid < 48) {
        const int j = j0 + tid;
        const int4 rj4 = *reinterpret_cast<const int4*>(rank + j * 4);
        const unsigned rpj = (unsigned)rj4.x | ((unsigned)rj4.y << 8) |
                             ((unsigned)rj4.z << 16) | ((unsigned)rj4.w << 24);
        float4 v;
        v.x = D[(size_t)bi * NB + j] + 1.0f;           // d_ij + MARGIN
        v.y = __uint_as_float(HB - rpj);
        v.z = __uint_as_float(~(rpj + hmi) & HB);      // gt[i,j] bits
        v.w = 0.f;
        jd[tid] = v;
    }

    const int ka = tid, kb = tid + 192;
    const float dika = D[(size_t)bi * NB + ka];
    const float dikb = D[(size_t)bi * NB + kb];
    const int4 ra4 = *reinterpret_cast<const int4*>(rank + ka * 4);
    const int4 rb4 = *reinterpret_cast<const int4*>(rank + kb * 4);
    const unsigned rpka = (unsigned)ra4.x | ((unsigned)ra4.y << 8) |
                          ((unsigned)ra4.z << 16) | ((unsigned)ra4.w << 24);
    const unsigned rpkb = (unsigned)rb4.x | ((unsigned)rb4.y << 8) |
                          ((unsigned)rb4.z << 16) | ((unsigned)rb4.w << 24);
    __syncthreads();

    float sa = 0.f, sb = 0.f;
    #pragma unroll 6
    for (int j = 0; j < 48; ++j) {
        const float4 d4 = jd[j];                        // broadcast ds_read_b128
        const unsigned hj  = __float_as_uint(d4.y);
        const unsigned mij = __float_as_uint(d4.z);
        const unsigned ba  = ((rpka + hj) ^ HB) & mij;  // gt[i,j] & gt[j,ka]
        const unsigned bb  = ((rpkb + hj) ^ HB) & mij;
        const float wa = wl[(ba * KMUL) >> 28];
        const float wb = wl[(bb * KMUL) >> 28];
        const float va = fmaxf(d4.x - dika, 0.f);
        const float vb = fmaxf(d4.x - dikb, 0.f);
        sa = fmaf(va, wa, sa);
        sb = fmaf(vb, wb, sb);
    }

    float t = sa + sb;
    #pragma unroll
    for (int off = 32; off > 0; off >>= 1)
        t += __shfl_down(t, off);
    if ((tid & 63) == 0) red[tid >> 6] = t;
    __syncthreads();
    if (tid == 0)
        atomicAdd(out, red[0] + red[1] + red[2]);
}

extern "C" void kernel_launch(void* const* d_in, const int* in_sizes, int n_in,
                              void* d_out, int out_size, void* d_ws, size_t ws_size,
                              hipStream_t stream)
{
    (void)in_sizes; (void)n_in; (void)out_size; (void)ws_size;
    const float* emb  = (const float*)d_in[0];
    const float* tw   = (const float*)d_in[1];
    const int*   rank = (const int*)d_in[2];
    float* ws  = (float*)d_ws;
    float* out = (float*)d_out;

    hipMemsetAsync(out, 0, sizeof(float), stream);
    dist_kernel<<<dim3(96, 3), 128, 0, stream>>>(emb, tw, rank, ws);
    mtrl_kernel<<<NB * 8, 192, 0, stream>>>(rank, ws, out);
}

// Round 3
// 43.625 us; speedup vs baseline: 1.6416x; 1.6416x over previous
//
#include <hip/hip_runtime.h>

#define NB    384          // batch
#define ND    256          // embedding dim
#define HB    0x80808080u  // byte-MSB mask
#define KMUL  0x00204081u  // gathers bits {7,15,23,31} -> {28..31}
#define EPSF  1e-6f
#define NPART 1536
#define WOFF  (16 + NPART) // float offset of packed jd[384*384] float4 array

// ws layout (floats): [0..16) wlut | [16..16+NPART) block partials
//                     | [WOFF..WOFF+384*384*4) jd float4 {d_ij+1, hj, bits_ij, 0}

// ---------------------------------------------------------------------------
// Kernel A: distances + per-(i,j) packed helpers. Block = 2 i-rows x 64 j.
// Grid (192, 6) = 1152 blocks (4.5 blocks/CU). Block (0,0) also builds wlut.
// ---------------------------------------------------------------------------
__global__ __launch_bounds__(128) void distpack_kernel(
    const float* __restrict__ emb,
    const float* __restrict__ tw,
    const int*   __restrict__ rank,
    float* __restrict__ ws)
{
    __shared__ float    ei[2 * ND];
    __shared__ unsigned hist[20];
    __shared__ double   wp[4];

    const int tid = threadIdx.x;       // 0..127
    const int i0  = blockIdx.x * 2;
    const int ii  = tid >> 6;
    const int i   = i0 + ii;
    const int j   = blockIdx.y * 64 + (tid & 63);

    if (tid < 20) hist[tid] = 0u;
    reinterpret_cast<float4*>(ei)[tid] =
        reinterpret_cast<const float4*>(emb + (size_t)i0 * ND)[tid];
    __syncthreads();

    const float4* ej4 = reinterpret_cast<const float4*>(emb + (size_t)j * ND);
    const float4* ei4 = reinterpret_cast<const float4*>(ei + ii * ND);
    float s = 0.f;
    #pragma unroll 8
    for (int d = 0; d < ND / 4; ++d) {
        float4 a = ei4[d];            // LDS broadcast (wave-uniform addr)
        float4 b = ej4[d];
        float dx = a.x - b.x + EPSF;
        float dy = a.y - b.y + EPSF;
        float dz = a.z - b.z + EPSF;
        float dw = a.w - b.w + EPSF;
        s = fmaf(dx, dx, s);
        s = fmaf(dy, dy, s);
        s = fmaf(dz, dz, s);
        s = fmaf(dw, dw, s);
    }

    const int4 ri4 = *reinterpret_cast<const int4*>(rank + i * 4);
    const unsigned rpi = (unsigned)ri4.x | ((unsigned)ri4.y << 8) |
                         ((unsigned)ri4.z << 16) | ((unsigned)ri4.w << 24);
    const unsigned hmi = HB - rpi;
    const int4 rj4 = *reinterpret_cast<const int4*>(rank + j * 4);
    const unsigned rpj = (unsigned)rj4.x | ((unsigned)rj4.y << 8) |
                         ((unsigned)rj4.z << 16) | ((unsigned)rj4.w << 24);
    float4 v;
    v.x = sqrtf(s) + 1.0f;                     // d_ij + MARGIN
    v.y = __uint_as_float(HB - rpj);           // hj
    v.z = __uint_as_float(~(rpj + hmi) & HB);  // gt[i,j] bits
    v.w = 0.f;
    reinterpret_cast<float4*>(ws + WOFF)[(size_t)i * NB + j] = v;

    // ---- block (0,0): wlut from analytic counts
    if (blockIdx.x == 0 && blockIdx.y == 0) {
        for (int e = tid; e < NB * 4; e += 128)
            atomicAdd(&hist[(e & 3) * 5 + rank[e]], 1u);
        __syncthreads();
        if (tid < 4) {
            double c = 0.0;
            unsigned below = 0;
            #pragma unroll
            for (int vv = 0; vv < 5; ++vv) {
                unsigned hv = hist[tid * 5 + vv];
                unsigned above = (unsigned)NB - below - hv;
                c += (double)hv * (double)below * (double)above;
                below += hv;
            }
            wp[tid] = (c > 0.0) ? (double)tw[tid] / c : 0.0;
        }
        __syncthreads();
        if (tid < 16) {
            double w = 0.0;
            if (tid & 1) w += wp[0];
            if (tid & 2) w += wp[1];
            if (tid & 4) w += wp[2];
            if (tid & 8) w += wp[3];
            ws[tid] = (float)w;        // wlut[0]==0 absorbs masked triples
        }
    }
}

// ---------------------------------------------------------------------------
// Kernel B: partial[b] = sum relu(d_ij - d_ik + 1) * wlut[bits_ij & bits_jk]
// Block = (i, 96-wide j-slice); thread owns k = tid and tid+192.
// Grid 1536 = exactly 6 blocks/CU, all co-resident. NO global atomics.
// ---------------------------------------------------------------------------
__global__ __launch_bounds__(192) void mtrl_kernel(
    const int*   __restrict__ rank,
    float* __restrict__ ws)
{
    __shared__ float4 jd[96];
    __shared__ float  wl[16];
    __shared__ float  red[3];

    const int tid = threadIdx.x;
    const int bi  = blockIdx.x >> 2;
    const int j0  = (blockIdx.x & 3) * 96;
    const float4* jrow = reinterpret_cast<const float4*>(ws + WOFF) + (size_t)bi * NB;

    if (tid < 16) wl[tid] = ws[tid];
    if (tid < 96) jd[tid] = jrow[j0 + tid];

    const int ka = tid, kb = tid + 192;
    const float dika = jrow[ka].x - 1.0f;     // raw d_ik
    const float dikb = jrow[kb].x - 1.0f;
    const int4 ra4 = *reinterpret_cast<const int4*>(rank + ka * 4);
    const int4 rb4 = *reinterpret_cast<const int4*>(rank + kb * 4);
    const unsigned rpka = (unsigned)ra4.x | ((unsigned)ra4.y << 8) |
                          ((unsigned)ra4.z << 16) | ((unsigned)ra4.w << 24);
    const unsigned rpkb = (unsigned)rb4.x | ((unsigned)rb4.y << 8) |
                          ((unsigned)rb4.z << 16) | ((unsigned)rb4.w << 24);
    __syncthreads();

    float sa = 0.f, sb = 0.f;
    #pragma unroll 8
    for (int j = 0; j < 96; ++j) {
        const float4 d4 = jd[j];                        // broadcast ds_read_b128
        const unsigned hj  = __float_as_uint(d4.y);
        const unsigned mij = __float_as_uint(d4.z);
        const unsigned ba  = ((rpka + hj) ^ HB) & mij;  // gt[i,j] & gt[j,ka]
        const unsigned bb  = ((rpkb + hj) ^ HB) & mij;
        const float wa = wl[(ba * KMUL) >> 28];
        const float wb = wl[(bb * KMUL) >> 28];
        const float va = fmaxf(d4.x - dika, 0.f);
        const float vb = fmaxf(d4.x - dikb, 0.f);
        sa = fmaf(va, wa, sa);
        sb = fmaf(vb, wb, sb);
    }

    float t = sa + sb;
    #pragma unroll
    for (int off = 32; off > 0; off >>= 1)
        t += __shfl_down(t, off);
    if ((tid & 63) == 0) red[tid >> 6] = t;
    __syncthreads();
    if (tid == 0)
        ws[16 + blockIdx.x] = red[0] + red[1] + red[2];  // partial, no atomic
}

// ---------------------------------------------------------------------------
// Kernel C: reduce 1536 partials -> out[0]
// ---------------------------------------------------------------------------
__global__ __launch_bounds__(256) void reduce_kernel(
    const float* __restrict__ ws, float* __restrict__ out)
{
    __shared__ float r[4];
    const int tid = threadIdx.x;
    float t = 0.f;
    #pragma unroll
    for (int p = tid; p < NPART; p += 256) t += ws[16 + p];
    #pragma unroll
    for (int off = 32; off > 0; off >>= 1)
        t += __shfl_down(t, off);
    if ((tid & 63) == 0) r[tid >> 6] = t;
    __syncthreads();
    if (tid == 0) out[0] = r[0] + r[1] + r[2] + r[3];
}

extern "C" void kernel_launch(void* const* d_in, const int* in_sizes, int n_in,
                              void* d_out, int out_size, void* d_ws, size_t ws_size,
                              hipStream_t stream)
{
    (void)in_sizes; (void)n_in; (void)out_size; (void)ws_size;
    const float* emb  = (const float*)d_in[0];
    const float* tw   = (const float*)d_in[1];
    const int*   rank = (const int*)d_in[2];
    float* ws  = (float*)d_ws;
    float* out = (float*)d_out;

    distpack_kernel<<<dim3(192, 6), 128, 0, stream>>>(emb, tw, rank, ws);
    mtrl_kernel<<<NB * 4, 192, 0, stream>>>(rank, ws);
    reduce_kernel<<<1, 256, 0, stream>>>(ws, out);
}